// Round 16
// baseline (126.115 us; speedup 1.0000x reference)
//
#include <hip/hip_runtime.h>

typedef float f32x4 __attribute__((ext_vector_type(4)));
typedef __bf16 bf16x8 __attribute__((ext_vector_type(8)));

#define DEV static __device__ __forceinline__

DEV ushort f2bf(float f) {
  unsigned u = __builtin_bit_cast(unsigned, f);
  u += 0x7FFFu + ((u >> 16) & 1u);
  return (ushort)(u >> 16);
}

DEV bf16x8 ld_frag(const ushort* p) {
  return __builtin_bit_cast(bf16x8, *reinterpret_cast<const int4*>(p));
}

DEV bf16x8 ld_lds(const ushort* base, int byte_off) {
  return __builtin_bit_cast(bf16x8,
      *reinterpret_cast<const int4*>(reinterpret_cast<const char*>(base) + byte_off));
}

// XOR swizzle for [rows][64] bf16 tiles (128B row stride). Paired with
// inverse-swizzled global SOURCE addresses + linear global_load_lds dest.
DEV int swz(int row, int col_byte) { return row * 128 + (col_byte ^ ((row & 7) << 4)); }

DEV float fast_exp2(float x) {
  float r;
  asm("v_exp_f32 %0, %1" : "=v"(r) : "v"(x));
  return r;
}

DEV unsigned cvt_pk_bf16(float lo, float hi) {
  unsigned r;
  asm("v_cvt_pk_bf16_f32 %0, %1, %2" : "=v"(r) : "v"(lo), "v"(hi));
  return r;
}

// async global->LDS, 16B per lane; LDS dest = uniform base + lane*16 (linear)
DEV void gload16(const ushort* g, ushort* l) {
  __builtin_amdgcn_global_load_lds(
      (const __attribute__((address_space(1))) unsigned int*)g,
      (__attribute__((address_space(3))) unsigned int*)l, 16, 0, 0);
}

// ---------------- prep: weight transposes (z=0..3) + x conversion (z=4..7) ----

__global__ __launch_bounds__(256) void prep(const float* __restrict__ x,
                                            const float* __restrict__ w0,
                                            const float* __restrict__ w1,
                                            const float* __restrict__ w2,
                                            const float* __restrict__ w3,
                                            ushort* __restrict__ xb,
                                            ushort* __restrict__ wt) {
  __shared__ float tile[32][33];
  const int z = blockIdx.z;
  const int tx = threadIdx.x, ty = threadIdx.y;  // block (8,32)
  if (z < 4) {
    const float* w = z == 0 ? w0 : z == 1 ? w1 : z == 2 ? w2 : w3;
    ushort* out = wt + (size_t)z * 1024 * 1024;
    const int n0 = blockIdx.x * 32, k0 = blockIdx.y * 32;
    float4 v = *reinterpret_cast<const float4*>(&w[(size_t)(k0 + ty) * 1024 + n0 + tx * 4]);
    tile[ty][tx * 4 + 0] = v.x;
    tile[ty][tx * 4 + 1] = v.y;
    tile[ty][tx * 4 + 2] = v.z;
    tile[ty][tx * 4 + 3] = v.w;
    __syncthreads();
    ushort4 o = make_ushort4(f2bf(tile[tx * 4 + 0][ty]), f2bf(tile[tx * 4 + 1][ty]),
                             f2bf(tile[tx * 4 + 2][ty]), f2bf(tile[tx * 4 + 3][ty]));
    *reinterpret_cast<ushort4*>(&out[(size_t)(n0 + ty) * 1024 + k0 + tx * 4]) = o;
  } else {
    const int blk = ((z - 4) * 32 + blockIdx.y) * 32 + blockIdx.x;  // 0..4095
    const int tid = ty * 8 + tx;
    const int i = blk * 256 + tid;
    float4 v = reinterpret_cast<const float4*>(x)[i];
    ushort4 o = make_ushort4(f2bf(v.x), f2bf(v.y), f2bf(v.z), f2bf(v.w));
    reinterpret_cast<ushort4*>(xb)[i] = o;
  }
}

// ---------------- fused QKV GEMM: 128x64 x 3 z's, DOUBLE-BUFFERED ----------------
// R14 geometry (proven best tile: 48 MFMA/wave/step, A staged once for 3 B's)
// + attn-style double buffering: stage(t+1) -> compute(t) -> one barrier, so
// loads land under a full 48-MFMA phase instead of a serial drain.
// LDS 80KB -> still 2 blocks/CU (free). Grid 512.
__global__ __launch_bounds__(256) void gemm_qkv(const ushort* __restrict__ xb,
                                                const ushort* __restrict__ wT,
                                                ushort* __restrict__ q, ushort* __restrict__ k,
                                                ushort* __restrict__ vt) {
  __shared__ ushort a_lds[2][128 * 64];
  __shared__ ushort b_lds[2][3][64 * 64];
  const int fid = blockIdx.x;
  const int wid = (fid & 7) * 64 + (fid >> 3);  // bijective: 8 XCDs x 64
  const int row0 = (wid >> 4) * 128, col0 = (wid & 15) * 64;
  const int tid = threadIdx.x;
  const int lane = tid & 63;
  const int w = tid >> 6, wr = w >> 1, wc = w & 1;
  const int lg = lane >> 4, l15 = lane & 15;
  const int sr8 = lane >> 3;
  const int scol = ((lane & 7) ^ sr8) << 3;  // pre-swizzled col (elems)
  const ushort* ga = xb + (size_t)(row0 + w * 32 + sr8) * 1024 + scol;
  const ushort* gb[3];
#pragma unroll
  for (int z = 0; z < 3; ++z)
    gb[z] = wT + (size_t)z * 1024 * 1024 + (size_t)(col0 + w * 16 + sr8) * 1024 + scol;

  f32x4 acc[3][4][2];
#pragma unroll
  for (int z = 0; z < 3; ++z)
#pragma unroll
    for (int ai = 0; ai < 4; ++ai)
#pragma unroll
      for (int bj = 0; bj < 2; ++bj) acc[z][ai][bj] = f32x4{0.f, 0.f, 0.f, 0.f};

  auto stage = [&](int buf, int kt) {
#pragma unroll
    for (int p = 0; p < 4; ++p)
      gload16(ga + kt + (size_t)(p * 8) * 1024, a_lds[buf] + (w * 32 + p * 8) * 64);
#pragma unroll
    for (int z = 0; z < 3; ++z)
#pragma unroll
      for (int p = 0; p < 2; ++p)
        gload16(gb[z] + kt + (size_t)(p * 8) * 1024, b_lds[buf][z] + (w * 16 + p * 8) * 64);
  };

  auto compute = [&](int buf) {
    bf16x8 af[4][2];
#pragma unroll
    for (int kk = 0; kk < 2; ++kk)
#pragma unroll
      for (int i = 0; i < 4; ++i)
        af[i][kk] = ld_lds(a_lds[buf], swz(wr * 64 + i * 16 + l15, kk * 64 + lg * 16));
#pragma unroll
    for (int z = 0; z < 3; ++z) {
      bf16x8 bfr[2][2];
#pragma unroll
      for (int kk = 0; kk < 2; ++kk)
#pragma unroll
        for (int j = 0; j < 2; ++j)
          bfr[j][kk] = ld_lds(b_lds[buf][z], swz(wc * 32 + j * 16 + l15, kk * 64 + lg * 16));
#pragma unroll
      for (int kk = 0; kk < 2; ++kk)
#pragma unroll
        for (int ai = 0; ai < 4; ++ai)
#pragma unroll
          for (int bj = 0; bj < 2; ++bj)
            acc[z][ai][bj] = __builtin_amdgcn_mfma_f32_16x16x32_bf16(af[ai][kk], bfr[bj][kk],
                                                                     acc[z][ai][bj], 0, 0, 0);
    }
  };

  stage(0, 0);
  __syncthreads();
  for (int t = 0; t < 8; ++t) {
    stage(1, (2 * t + 1) * 64);
    compute(0);
    __syncthreads();
    if (t < 7) stage(0, (2 * t + 2) * 64);
    compute(1);
    __syncthreads();
  }

  // epilogues: z=0 -> Q (scaled by 0.125*log2e), z=1 -> K, z=2 -> V^T per head
#pragma unroll
  for (int z = 0; z < 2; ++z) {
    ushort* out = z == 0 ? q : k;
    const float sc = z == 0 ? 0.125f * 1.4426950408889634f : 1.0f;
#pragma unroll
    for (int ai = 0; ai < 4; ++ai)
#pragma unroll
      for (int bj = 0; bj < 2; ++bj)
#pragma unroll
        for (int r = 0; r < 4; ++r) {
          int orow = row0 + wr * 64 + ai * 16 + lg * 4 + r;
          int ocol = col0 + wc * 32 + bj * 16 + l15;
          out[(size_t)orow * 1024 + ocol] = f2bf(acc[z][ai][bj][r] * sc);
        }
  }
#pragma unroll
  for (int ai = 0; ai < 4; ++ai)
#pragma unroll
    for (int bj = 0; bj < 2; ++bj) {
      int orow = row0 + wr * 64 + ai * 16 + lg * 4;
      int ocol = col0 + wc * 32 + bj * 16 + l15;
      int bb = orow >> 11, n = orow & 2047;
      ushort4 pk = make_ushort4(f2bf(acc[2][ai][bj][0]), f2bf(acc[2][ai][bj][1]),
                                f2bf(acc[2][ai][bj][2]), f2bf(acc[2][ai][bj][3]));
      *reinterpret_cast<ushort4*>(vt + ((size_t)(bb * 1024 + ocol)) * 2048 + n) = pk;
    }
}

// final GEMM: y = x + O*Wp. 64x64 tiles, DOUBLE-BUFFERED, 1024 blocks (4/CU).
__global__ __launch_bounds__(256) void gemm_out(const ushort* __restrict__ ob,
                                                const ushort* __restrict__ wpT,
                                                const float* __restrict__ x,
                                                float* __restrict__ y) {
  __shared__ ushort a_lds[2][64 * 64], b_lds[2][64 * 64];
  const int fid = blockIdx.x;
  const int wid = (fid & 7) * 128 + (fid >> 3);  // bijective: 8 XCDs x 128
  const int row0 = (wid >> 4) * 64, col0 = (wid & 15) * 64;
  const int tid = threadIdx.x;
  const int lane = tid & 63;
  const int w = tid >> 6, wr = w >> 1, wc = w & 1;
  const int lg = lane >> 4, l15 = lane & 15;
  const int sr8 = lane >> 3;
  const int scol = ((lane & 7) ^ sr8) << 3;
  const ushort* ga = ob + (size_t)(row0 + w * 16 + sr8) * 1024 + scol;
  const ushort* gb = wpT + (size_t)(col0 + w * 16 + sr8) * 1024 + scol;

  f32x4 acc[2][2];
#pragma unroll
  for (int ai = 0; ai < 2; ++ai)
#pragma unroll
    for (int bj = 0; bj < 2; ++bj) acc[ai][bj] = f32x4{0.f, 0.f, 0.f, 0.f};

  auto stage = [&](int buf, int kt) {
#pragma unroll
    for (int p = 0; p < 2; ++p) {
      gload16(ga + kt + (size_t)(p * 8) * 1024, a_lds[buf] + (w * 16 + p * 8) * 64);
      gload16(gb + kt + (size_t)(p * 8) * 1024, b_lds[buf] + (w * 16 + p * 8) * 64);
    }
  };

  auto compute = [&](int buf) {
    bf16x8 af[2][2], bfr[2][2];
#pragma unroll
    for (int kk = 0; kk < 2; ++kk) {
#pragma unroll
      for (int i = 0; i < 2; ++i) {
        af[i][kk] = ld_lds(a_lds[buf], swz(wr * 32 + i * 16 + l15, kk * 64 + lg * 16));
        bfr[i][kk] = ld_lds(b_lds[buf], swz(wc * 32 + i * 16 + l15, kk * 64 + lg * 16));
      }
    }
#pragma unroll
    for (int kk = 0; kk < 2; ++kk)
#pragma unroll
      for (int ai = 0; ai < 2; ++ai)
#pragma unroll
        for (int bj = 0; bj < 2; ++bj)
          acc[ai][bj] = __builtin_amdgcn_mfma_f32_16x16x32_bf16(af[ai][kk], bfr[bj][kk],
                                                                acc[ai][bj], 0, 0, 0);
  };

  stage(0, 0);
  __syncthreads();
  for (int t = 0; t < 8; ++t) {
    stage(1, (2 * t + 1) * 64);
    compute(0);
    __syncthreads();
    if (t < 7) stage(0, (2 * t + 2) * 64);
    compute(1);
    __syncthreads();
  }

#pragma unroll
  for (int ai = 0; ai < 2; ++ai)
#pragma unroll
    for (int bj = 0; bj < 2; ++bj)
#pragma unroll
      for (int r = 0; r < 4; ++r) {
        int orow = row0 + wr * 32 + ai * 16 + lg * 4 + r;
        int ocol = col0 + wc * 32 + bj * 16 + l15;
        size_t idx = (size_t)orow * 1024 + ocol;
        y[idx] = x[idx] + acc[ai][bj][r];
      }
}

// ---------------- flash attention: R13 (51.5us; R8 geometry + neutral SGB) ----
__global__ __launch_bounds__(256) void attn(const ushort* __restrict__ qg,
                                            const ushort* __restrict__ kg,
                                            const ushort* __restrict__ vtg,
                                            ushort* __restrict__ og) {
  __shared__ ushort k_lds[4 * 64 * 64];  // [buf][sub] 4 x 8KB
  __shared__ ushort v_lds[4 * 64 * 64];
  const int fid = blockIdx.x;
  const int wid = (fid & 7) * 64 + (fid >> 3);  // bijective: 8 XCDs x 64
  const int bh = wid >> 4, q0 = wid & 15;
  const int b = bh >> 4, h = bh & 15;
  const int n0 = q0 * 128;
  const int tid = threadIdx.x, lane = tid & 63, w = tid >> 6;
  const int lg = lane >> 4, l15 = lane & 15;

  bf16x8 qf[2][2];
#pragma unroll
  for (int qi = 0; qi < 2; ++qi)
#pragma unroll
    for (int d32 = 0; d32 < 2; ++d32)
      qf[qi][d32] = ld_frag(qg + (size_t)(b * 2048 + n0 + w * 32 + qi * 16 + l15) * 1024 +
                            h * 64 + d32 * 32 + lg * 8);

  f32x4 o[2][4];
#pragma unroll
  for (int qi = 0; qi < 2; ++qi)
#pragma unroll
    for (int bj = 0; bj < 4; ++bj) o[qi][bj] = f32x4{0.f, 0.f, 0.f, 0.f};
  f32x4 ssum[2] = {f32x4{0.f, 0.f, 0.f, 0.f}, f32x4{0.f, 0.f, 0.f, 0.f}};

  const int sr8 = lane >> 3;
  const int scol = ((lane & 7) ^ sr8) << 3;  // pre-swizzled col (elems)
  const ushort* kbase = kg + (size_t)(b * 2048 + w * 16 + sr8) * 1024 + h * 64 + scol;
  const ushort* vbase = vtg + (size_t)(b * 1024 + h * 64 + w * 16 + sr8) * 2048 + scol;

  auto stage_sub = [&](ushort* kdst, ushort* vdst, int kv0) {
#pragma unroll
    for (int p = 0; p < 2; ++p) {
      gload16(kbase + (size_t)(kv0 + p * 8) * 1024, kdst + (w * 16 + p * 8) * 64);
      gload16(vbase + (size_t)(p * 8) * 2048 + kv0, vdst + (w * 16 + p * 8) * 64);
    }
  };
  auto stage2 = [&](int buf, int kv0) {
    stage_sub(k_lds + (2 * buf) * 4096, v_lds + (2 * buf) * 4096, kv0);
    stage_sub(k_lds + (2 * buf + 1) * 4096, v_lds + (2 * buf + 1) * 4096, kv0 + 64);
  };

  const int4 ones4 = make_int4(0x3F803F80, 0x3F803F80, 0x3F803F80, 0x3F803F80);
  const bf16x8 onesf = __builtin_bit_cast(bf16x8, ones4);

  auto qk_sub = [&](const ushort* kb, f32x4 s[2][4]) {
#pragma unroll
    for (int qi = 0; qi < 2; ++qi)
#pragma unroll
      for (int kj = 0; kj < 4; ++kj) s[qi][kj] = f32x4{0.f, 0.f, 0.f, 0.f};
#pragma unroll
    for (int d32 = 0; d32 < 2; ++d32)
#pragma unroll
      for (int kj = 0; kj < 4; ++kj) {
        bf16x8 kf = ld_lds(kb, swz(kj * 16 + l15, d32 * 64 + lg * 16));
        s[0][kj] = __builtin_amdgcn_mfma_f32_16x16x32_bf16(kf, qf[0][d32], s[0][kj], 0, 0, 0);
        s[1][kj] = __builtin_amdgcn_mfma_f32_16x16x32_bf16(kf, qf[1][d32], s[1][kj], 0, 0, 0);
      }
  };

  auto exp_pack = [&](f32x4 s[2][4], bf16x8 pa[2][2]) {
#pragma unroll
    for (int qi = 0; qi < 2; ++qi) {
      unsigned pk[4][2];
#pragma unroll
      for (int kj = 0; kj < 4; ++kj) {
        float p0 = fast_exp2(s[qi][kj][0]);
        float p1 = fast_exp2(s[qi][kj][1]);
        float p2 = fast_exp2(s[qi][kj][2]);
        float p3 = fast_exp2(s[qi][kj][3]);
        pk[kj][0] = cvt_pk_bf16(p0, p1);
        pk[kj][1] = cvt_pk_bf16(p2, p3);
      }
#pragma unroll
      for (int k32 = 0; k32 < 2; ++k32) {
        unsigned x0 = pk[2 * k32][0], y0 = pk[2 * k32 + 1][0];
        unsigned x1 = pk[2 * k32][1], y1 = pk[2 * k32 + 1][1];
        asm("v_permlane32_swap_b32 %0, %1" : "+v"(x0), "+v"(y0));
        asm("v_permlane32_swap_b32 %0, %1" : "+v"(x1), "+v"(y1));
        asm("v_permlane16_swap_b32 %0, %1" : "+v"(x0), "+v"(y0));
        asm("v_permlane16_swap_b32 %0, %1" : "+v"(x1), "+v"(y1));
        int4 fr = make_int4(x0, x1, y0, y1);
        pa[qi][k32] = __builtin_bit_cast(bf16x8, fr);
      }
    }
  };

  auto pv_only = [&](const ushort* vb, bf16x8 pa[2][2]) {
#pragma unroll
    for (int qi = 0; qi < 2; ++qi) {
      ssum[qi] = __builtin_amdgcn_mfma_f32_16x16x32_bf16(pa[qi][0], onesf, ssum[qi], 0, 0, 0);
      ssum[qi] = __builtin_amdgcn_mfma_f32_16x16x32_bf16(pa[qi][1], onesf, ssum[qi], 0, 0, 0);
    }
#pragma unroll
    for (int k32 = 0; k32 < 2; ++k32)
#pragma unroll
      for (int bj = 0; bj < 4; ++bj) {
        bf16x8 vf = ld_lds(vb, swz(bj * 16 + l15, k32 * 64 + lg * 16));
        o[0][bj] = __builtin_amdgcn_mfma_f32_16x16x32_bf16(pa[0][k32], vf, o[0][bj], 0, 0, 0);
        o[1][bj] = __builtin_amdgcn_mfma_f32_16x16x32_bf16(pa[1][k32], vf, o[1][bj], 0, 0, 0);
      }
  };

  auto body2 = [&](int buf) {
    const ushort* kb0 = k_lds + (2 * buf) * 4096;
    const ushort* kb1 = k_lds + (2 * buf + 1) * 4096;
    const ushort* vb0 = v_lds + (2 * buf) * 4096;
    const ushort* vb1 = v_lds + (2 * buf + 1) * 4096;
    f32x4 s0[2][4], s1[2][4];
    bf16x8 pa0[2][2], pa1[2][2];
    qk_sub(kb0, s0);
    qk_sub(kb1, s1);
    exp_pack(s0, pa0);
    pv_only(vb0, pa0);
    exp_pack(s1, pa1);
    pv_only(vb1, pa1);
    __builtin_amdgcn_sched_group_barrier(0x020, 8, 0);   // stage VMEM first
    __builtin_amdgcn_sched_group_barrier(0x100, 8, 0);   // K0 ds_reads
    __builtin_amdgcn_sched_group_barrier(0x008, 16, 0);  // QK(s0)
    __builtin_amdgcn_sched_group_barrier(0x100, 8, 0);   // K1 ds_reads
#pragma unroll
    for (int i = 0; i < 16; ++i) {                       // QK(s1) || exp(s0)
      __builtin_amdgcn_sched_group_barrier(0x008, 1, 0);
      __builtin_amdgcn_sched_group_barrier(0x002, 4, 0);
    }
    __builtin_amdgcn_sched_group_barrier(0x100, 8, 0);   // V0 ds_reads
#pragma unroll
    for (int i = 0; i < 20; ++i) {                       // PV(s0) || exp(s1)
      __builtin_amdgcn_sched_group_barrier(0x008, 1, 0);
      __builtin_amdgcn_sched_group_barrier(0x002, 3, 0);
    }
    __builtin_amdgcn_sched_group_barrier(0x100, 8, 0);   // V1 ds_reads
    __builtin_amdgcn_sched_group_barrier(0x008, 20, 0);  // PV(s1)
  };

  stage2(0, 0);
  __syncthreads();

  for (int tt = 0; tt < 8; ++tt) {
    stage2(1, (2 * tt + 1) * 128);
    body2(0);
    __syncthreads();
    if (tt < 7) stage2(0, (2 * tt + 2) * 128);
    body2(1);
    __syncthreads();
  }

#pragma unroll
  for (int qi = 0; qi < 2; ++qi) {
    f32x4 inv;
#pragma unroll
    for (int r = 0; r < 4; ++r) inv[r] = 1.0f / ssum[qi][r];
#pragma unroll
    for (int bj = 0; bj < 4; ++bj)
#pragma unroll
      for (int r = 0; r < 4; ++r) {
        int n = n0 + w * 32 + qi * 16 + lg * 4 + r;
        og[(size_t)(b * 2048 + n) * 1024 + h * 64 + bj * 16 + l15] = f2bf(o[qi][bj][r] * inv[r]);
      }
  }
}

// ---------------- launch ----------------

extern "C" void kernel_launch(void* const* d_in, const int* in_sizes, int n_in,
                              void* d_out, int out_size, void* d_ws, size_t ws_size,
                              hipStream_t stream) {
  const float* x = (const float*)d_in[0];
  const float* Wq = (const float*)d_in[1];
  const float* Wk = (const float*)d_in[2];
  const float* Wv = (const float*)d_in[3];
  const float* Wp = (const float*)d_in[4];
  float* y = (float*)d_out;

  char* ws = (char*)d_ws;
  ushort* xb = (ushort*)(ws);
  ushort* wT = (ushort*)(ws + (8ull << 20));
  ushort* qw = (ushort*)(ws + (16ull << 20));
  ushort* kw = (ushort*)(ws + (24ull << 20));
  ushort* vtw = (ushort*)(ws + (32ull << 20));
  ushort* ow = (ushort*)(ws);  // reuse xb region (dead after gemm_qkv)

  prep<<<dim3(32, 32, 8), dim3(8, 32), 0, stream>>>(x, Wq, Wk, Wv, Wp, xb, wT);
  gemm_qkv<<<512, 256, 0, stream>>>(xb, wT, qw, kw, vtw);
  attn<<<512, 256, 0, stream>>>(qw, kw, vtw, ow);
  gemm_out<<<1024, 256, 0, stream>>>(ow, wT + (3u << 20), x, y);
}

// Round 17
// 102.013 us; speedup vs baseline: 1.2363x; 1.2363x over previous
//
#include <hip/hip_runtime.h>

typedef float f32x4 __attribute__((ext_vector_type(4)));
typedef __bf16 bf16x8 __attribute__((ext_vector_type(8)));

#define DEV static __device__ __forceinline__

DEV ushort f2bf(float f) {
  unsigned u = __builtin_bit_cast(unsigned, f);
  u += 0x7FFFu + ((u >> 16) & 1u);
  return (ushort)(u >> 16);
}

DEV bf16x8 ld_frag(const ushort* p) {
  return __builtin_bit_cast(bf16x8, *reinterpret_cast<const int4*>(p));
}

DEV bf16x8 ld_lds(const ushort* base, int byte_off) {
  return __builtin_bit_cast(bf16x8,
      *reinterpret_cast<const int4*>(reinterpret_cast<const char*>(base) + byte_off));
}

// XOR swizzle for [rows][64] bf16 tiles (128B row stride). Paired with
// inverse-swizzled global SOURCE addresses + linear global_load_lds dest.
DEV int swz(int row, int col_byte) { return row * 128 + (col_byte ^ ((row & 7) << 4)); }

DEV float fast_exp2(float x) {
  float r;
  asm("v_exp_f32 %0, %1" : "=v"(r) : "v"(x));
  return r;
}

DEV unsigned cvt_pk_bf16(float lo, float hi) {
  unsigned r;
  asm("v_cvt_pk_bf16_f32 %0, %1, %2" : "=v"(r) : "v"(lo), "v"(hi));
  return r;
}

// async global->LDS, 16B per lane; LDS dest = uniform base + lane*16 (linear)
DEV void gload16(const ushort* g, ushort* l) {
  __builtin_amdgcn_global_load_lds(
      (const __attribute__((address_space(1))) unsigned int*)g,
      (__attribute__((address_space(3))) unsigned int*)l, 16, 0, 0);
}

// ---------------- prep: weight transposes (z=0..3) + x conversion (z=4..7) ----

__global__ __launch_bounds__(256) void prep(const float* __restrict__ x,
                                            const float* __restrict__ w0,
                                            const float* __restrict__ w1,
                                            const float* __restrict__ w2,
                                            const float* __restrict__ w3,
                                            ushort* __restrict__ xb,
                                            ushort* __restrict__ wt) {
  __shared__ float tile[32][33];
  const int z = blockIdx.z;
  const int tx = threadIdx.x, ty = threadIdx.y;  // block (8,32)
  if (z < 4) {
    const float* w = z == 0 ? w0 : z == 1 ? w1 : z == 2 ? w2 : w3;
    ushort* out = wt + (size_t)z * 1024 * 1024;
    const int n0 = blockIdx.x * 32, k0 = blockIdx.y * 32;
    float4 v = *reinterpret_cast<const float4*>(&w[(size_t)(k0 + ty) * 1024 + n0 + tx * 4]);
    tile[ty][tx * 4 + 0] = v.x;
    tile[ty][tx * 4 + 1] = v.y;
    tile[ty][tx * 4 + 2] = v.z;
    tile[ty][tx * 4 + 3] = v.w;
    __syncthreads();
    ushort4 o = make_ushort4(f2bf(tile[tx * 4 + 0][ty]), f2bf(tile[tx * 4 + 1][ty]),
                             f2bf(tile[tx * 4 + 2][ty]), f2bf(tile[tx * 4 + 3][ty]));
    *reinterpret_cast<ushort4*>(&out[(size_t)(n0 + ty) * 1024 + k0 + tx * 4]) = o;
  } else {
    const int blk = ((z - 4) * 32 + blockIdx.y) * 32 + blockIdx.x;  // 0..4095
    const int tid = ty * 8 + tx;
    const int i = blk * 256 + tid;
    float4 v = reinterpret_cast<const float4*>(x)[i];
    ushort4 o = make_ushort4(f2bf(v.x), f2bf(v.y), f2bf(v.z), f2bf(v.w));
    reinterpret_cast<ushort4*>(xb)[i] = o;
  }
}

// ---------------- fused QKV GEMM: one block does Q,K,V for its 128x64 tile ----
// R14 geometry (proven 102.8us config): A (xb) staged ONCE per K-step, reused
// for 3 B-tiles: 48 MFMA/wave per barrier pair, 40KB LDS, 2 blocks/CU.
// NEW: 8x8-per-XCD block mapping (was 4x16) -- per-XCD working set drops
// 7MB -> 5MB (2MB A rows + 3MB B panels), cutting L2 thrash (R16 FETCH=53MB).
__global__ __launch_bounds__(256) void gemm_qkv(const ushort* __restrict__ xb,
                                                const ushort* __restrict__ wT,
                                                ushort* __restrict__ q, ushort* __restrict__ k,
                                                ushort* __restrict__ vt) {
  __shared__ ushort a_lds[128 * 64];
  __shared__ ushort b_lds[3][64 * 64];
  const int fid = blockIdx.x;
  const int xcd = fid & 7, j = fid >> 3;       // 8 XCDs x 64 blocks
  const int row = (xcd & 3) * 8 + (j >> 3);    // 32 row-blocks (128 rows each)
  const int col = (xcd >> 2) * 8 + (j & 7);    // 16 col-blocks (64 cols each)
  const int row0 = row * 128, col0 = col * 64;
  const int tid = threadIdx.x;
  const int lane = tid & 63;
  const int w = tid >> 6, wr = w >> 1, wc = w & 1;
  const int lg = lane >> 4, l15 = lane & 15;
  const int sr8 = lane >> 3;
  const int scol = ((lane & 7) ^ sr8) << 3;  // pre-swizzled col (elems)
  const ushort* ga = xb + (size_t)(row0 + w * 32 + sr8) * 1024 + scol;
  const ushort* gb[3];
#pragma unroll
  for (int z = 0; z < 3; ++z)
    gb[z] = wT + (size_t)z * 1024 * 1024 + (size_t)(col0 + w * 16 + sr8) * 1024 + scol;

  f32x4 acc[3][4][2];
#pragma unroll
  for (int z = 0; z < 3; ++z)
#pragma unroll
    for (int ai = 0; ai < 4; ++ai)
#pragma unroll
      for (int bj = 0; bj < 2; ++bj) acc[z][ai][bj] = f32x4{0.f, 0.f, 0.f, 0.f};

  for (int kt = 0; kt < 1024; kt += 64) {
    __syncthreads();
#pragma unroll
    for (int p = 0; p < 4; ++p)
      gload16(ga + kt + (size_t)(p * 8) * 1024, a_lds + (w * 32 + p * 8) * 64);
#pragma unroll
    for (int z = 0; z < 3; ++z)
#pragma unroll
      for (int p = 0; p < 2; ++p)
        gload16(gb[z] + kt + (size_t)(p * 8) * 1024, b_lds[z] + (w * 16 + p * 8) * 64);
    __syncthreads();
    bf16x8 af[4][2];
#pragma unroll
    for (int kk = 0; kk < 2; ++kk)
#pragma unroll
      for (int i = 0; i < 4; ++i)
        af[i][kk] = ld_lds(a_lds, swz(wr * 64 + i * 16 + l15, kk * 64 + lg * 16));
#pragma unroll
    for (int z = 0; z < 3; ++z) {
      bf16x8 bfr[2][2];
#pragma unroll
      for (int kk = 0; kk < 2; ++kk)
#pragma unroll
        for (int j2 = 0; j2 < 2; ++j2)
          bfr[j2][kk] = ld_lds(b_lds[z], swz(wc * 32 + j2 * 16 + l15, kk * 64 + lg * 16));
#pragma unroll
      for (int kk = 0; kk < 2; ++kk)
#pragma unroll
        for (int ai = 0; ai < 4; ++ai)
#pragma unroll
          for (int bj = 0; bj < 2; ++bj)
            acc[z][ai][bj] = __builtin_amdgcn_mfma_f32_16x16x32_bf16(af[ai][kk], bfr[bj][kk],
                                                                     acc[z][ai][bj], 0, 0, 0);
    }
  }

  // epilogues: z=0 -> Q (scaled by 0.125*log2e), z=1 -> K, z=2 -> V^T per head
#pragma unroll
  for (int z = 0; z < 2; ++z) {
    ushort* out = z == 0 ? q : k;
    const float sc = z == 0 ? 0.125f * 1.4426950408889634f : 1.0f;
#pragma unroll
    for (int ai = 0; ai < 4; ++ai)
#pragma unroll
      for (int bj = 0; bj < 2; ++bj)
#pragma unroll
        for (int r = 0; r < 4; ++r) {
          int orow = row0 + wr * 64 + ai * 16 + lg * 4 + r;
          int ocol = col0 + wc * 32 + bj * 16 + l15;
          out[(size_t)orow * 1024 + ocol] = f2bf(acc[z][ai][bj][r] * sc);
        }
  }
#pragma unroll
  for (int ai = 0; ai < 4; ++ai)
#pragma unroll
    for (int bj = 0; bj < 2; ++bj) {
      int orow = row0 + wr * 64 + ai * 16 + lg * 4;
      int ocol = col0 + wc * 32 + bj * 16 + l15;
      int bb = orow >> 11, n = orow & 2047;
      ushort4 pk = make_ushort4(f2bf(acc[2][ai][bj][0]), f2bf(acc[2][ai][bj][1]),
                                f2bf(acc[2][ai][bj][2]), f2bf(acc[2][ai][bj][3]));
      *reinterpret_cast<ushort4*>(vt + ((size_t)(bb * 1024 + ocol)) * 2048 + n) = pk;
    }
}

// final GEMM: y = x + O*Wp. 64x64 tiles -> 1024 blocks (4/CU). R14 config.
__global__ __launch_bounds__(256) void gemm_out(const ushort* __restrict__ ob,
                                                const ushort* __restrict__ wpT,
                                                const float* __restrict__ x,
                                                float* __restrict__ y) {
  __shared__ ushort a_lds[64 * 64], b_lds[64 * 64];
  const int fid = blockIdx.x;
  const int wid = (fid & 7) * 128 + (fid >> 3);  // bijective: 8 XCDs x 128
  const int row0 = (wid >> 4) * 64, col0 = (wid & 15) * 64;
  const int tid = threadIdx.x;
  const int lane = tid & 63;
  const int w = tid >> 6, wr = w >> 1, wc = w & 1;
  const int lg = lane >> 4, l15 = lane & 15;
  const int sr8 = lane >> 3;
  const int scol = ((lane & 7) ^ sr8) << 3;
  const ushort* ga = ob + (size_t)(row0 + w * 16 + sr8) * 1024 + scol;
  const ushort* gb = wpT + (size_t)(col0 + w * 16 + sr8) * 1024 + scol;

  f32x4 acc[2][2];
#pragma unroll
  for (int ai = 0; ai < 2; ++ai)
#pragma unroll
    for (int bj = 0; bj < 2; ++bj) acc[ai][bj] = f32x4{0.f, 0.f, 0.f, 0.f};

  for (int kt = 0; kt < 1024; kt += 64) {
    __syncthreads();
#pragma unroll
    for (int p = 0; p < 2; ++p) {
      gload16(ga + kt + (size_t)(p * 8) * 1024, a_lds + (w * 16 + p * 8) * 64);
      gload16(gb + kt + (size_t)(p * 8) * 1024, b_lds + (w * 16 + p * 8) * 64);
    }
    __syncthreads();
    bf16x8 af[2][2], bfr[2][2];
#pragma unroll
    for (int kk = 0; kk < 2; ++kk) {
#pragma unroll
      for (int i = 0; i < 2; ++i) {
        af[i][kk] = ld_lds(a_lds, swz(wr * 32 + i * 16 + l15, kk * 64 + lg * 16));
        bfr[i][kk] = ld_lds(b_lds, swz(wc * 32 + i * 16 + l15, kk * 64 + lg * 16));
      }
    }
#pragma unroll
    for (int kk = 0; kk < 2; ++kk)
#pragma unroll
      for (int ai = 0; ai < 2; ++ai)
#pragma unroll
        for (int bj = 0; bj < 2; ++bj)
          acc[ai][bj] = __builtin_amdgcn_mfma_f32_16x16x32_bf16(af[ai][kk], bfr[bj][kk],
                                                                acc[ai][bj], 0, 0, 0);
  }

#pragma unroll
  for (int ai = 0; ai < 2; ++ai)
#pragma unroll
    for (int bj = 0; bj < 2; ++bj)
#pragma unroll
      for (int r = 0; r < 4; ++r) {
        int orow = row0 + wr * 32 + ai * 16 + lg * 4 + r;
        int ocol = col0 + wc * 32 + bj * 16 + l15;
        size_t idx = (size_t)orow * 1024 + ocol;
        y[idx] = x[idx] + acc[ai][bj][r];
      }
}

// ---------------- flash attention: R13 (51.5us; R8 geometry + neutral SGB) ----
__global__ __launch_bounds__(256) void attn(const ushort* __restrict__ qg,
                                            const ushort* __restrict__ kg,
                                            const ushort* __restrict__ vtg,
                                            ushort* __restrict__ og) {
  __shared__ ushort k_lds[4 * 64 * 64];  // [buf][sub] 4 x 8KB
  __shared__ ushort v_lds[4 * 64 * 64];
  const int fid = blockIdx.x;
  const int wid = (fid & 7) * 64 + (fid >> 3);  // bijective: 8 XCDs x 64
  const int bh = wid >> 4, q0 = wid & 15;
  const int b = bh >> 4, h = bh & 15;
  const int n0 = q0 * 128;
  const int tid = threadIdx.x, lane = tid & 63, w = tid >> 6;
  const int lg = lane >> 4, l15 = lane & 15;

  bf16x8 qf[2][2];
#pragma unroll
  for (int qi = 0; qi < 2; ++qi)
#pragma unroll
    for (int d32 = 0; d32 < 2; ++d32)
      qf[qi][d32] = ld_frag(qg + (size_t)(b * 2048 + n0 + w * 32 + qi * 16 + l15) * 1024 +
                            h * 64 + d32 * 32 + lg * 8);

  f32x4 o[2][4];
#pragma unroll
  for (int qi = 0; qi < 2; ++qi)
#pragma unroll
    for (int bj = 0; bj < 4; ++bj) o[qi][bj] = f32x4{0.f, 0.f, 0.f, 0.f};
  f32x4 ssum[2] = {f32x4{0.f, 0.f, 0.f, 0.f}, f32x4{0.f, 0.f, 0.f, 0.f}};

  const int sr8 = lane >> 3;
  const int scol = ((lane & 7) ^ sr8) << 3;  // pre-swizzled col (elems)
  const ushort* kbase = kg + (size_t)(b * 2048 + w * 16 + sr8) * 1024 + h * 64 + scol;
  const ushort* vbase = vtg + (size_t)(b * 1024 + h * 64 + w * 16 + sr8) * 2048 + scol;

  auto stage_sub = [&](ushort* kdst, ushort* vdst, int kv0) {
#pragma unroll
    for (int p = 0; p < 2; ++p) {
      gload16(kbase + (size_t)(kv0 + p * 8) * 1024, kdst + (w * 16 + p * 8) * 64);
      gload16(vbase + (size_t)(p * 8) * 2048 + kv0, vdst + (w * 16 + p * 8) * 64);
    }
  };
  auto stage2 = [&](int buf, int kv0) {
    stage_sub(k_lds + (2 * buf) * 4096, v_lds + (2 * buf) * 4096, kv0);
    stage_sub(k_lds + (2 * buf + 1) * 4096, v_lds + (2 * buf + 1) * 4096, kv0 + 64);
  };

  const int4 ones4 = make_int4(0x3F803F80, 0x3F803F80, 0x3F803F80, 0x3F803F80);
  const bf16x8 onesf = __builtin_bit_cast(bf16x8, ones4);

  auto qk_sub = [&](const ushort* kb, f32x4 s[2][4]) {
#pragma unroll
    for (int qi = 0; qi < 2; ++qi)
#pragma unroll
      for (int kj = 0; kj < 4; ++kj) s[qi][kj] = f32x4{0.f, 0.f, 0.f, 0.f};
#pragma unroll
    for (int d32 = 0; d32 < 2; ++d32)
#pragma unroll
      for (int kj = 0; kj < 4; ++kj) {
        bf16x8 kf = ld_lds(kb, swz(kj * 16 + l15, d32 * 64 + lg * 16));
        s[0][kj] = __builtin_amdgcn_mfma_f32_16x16x32_bf16(kf, qf[0][d32], s[0][kj], 0, 0, 0);
        s[1][kj] = __builtin_amdgcn_mfma_f32_16x16x32_bf16(kf, qf[1][d32], s[1][kj], 0, 0, 0);
      }
  };

  auto exp_pack = [&](f32x4 s[2][4], bf16x8 pa[2][2]) {
#pragma unroll
    for (int qi = 0; qi < 2; ++qi) {
      unsigned pk[4][2];
#pragma unroll
      for (int kj = 0; kj < 4; ++kj) {
        float p0 = fast_exp2(s[qi][kj][0]);
        float p1 = fast_exp2(s[qi][kj][1]);
        float p2 = fast_exp2(s[qi][kj][2]);
        float p3 = fast_exp2(s[qi][kj][3]);
        pk[kj][0] = cvt_pk_bf16(p0, p1);
        pk[kj][1] = cvt_pk_bf16(p2, p3);
      }
#pragma unroll
      for (int k32 = 0; k32 < 2; ++k32) {
        unsigned x0 = pk[2 * k32][0], y0 = pk[2 * k32 + 1][0];
        unsigned x1 = pk[2 * k32][1], y1 = pk[2 * k32 + 1][1];
        asm("v_permlane32_swap_b32 %0, %1" : "+v"(x0), "+v"(y0));
        asm("v_permlane32_swap_b32 %0, %1" : "+v"(x1), "+v"(y1));
        asm("v_permlane16_swap_b32 %0, %1" : "+v"(x0), "+v"(y0));
        asm("v_permlane16_swap_b32 %0, %1" : "+v"(x1), "+v"(y1));
        int4 fr = make_int4(x0, x1, y0, y1);
        pa[qi][k32] = __builtin_bit_cast(bf16x8, fr);
      }
    }
  };

  auto pv_only = [&](const ushort* vb, bf16x8 pa[2][2]) {
#pragma unroll
    for (int qi = 0; qi < 2; ++qi) {
      ssum[qi] = __builtin_amdgcn_mfma_f32_16x16x32_bf16(pa[qi][0], onesf, ssum[qi], 0, 0, 0);
      ssum[qi] = __builtin_amdgcn_mfma_f32_16x16x32_bf16(pa[qi][1], onesf, ssum[qi], 0, 0, 0);
    }
#pragma unroll
    for (int k32 = 0; k32 < 2; ++k32)
#pragma unroll
      for (int bj = 0; bj < 4; ++bj) {
        bf16x8 vf = ld_lds(vb, swz(bj * 16 + l15, k32 * 64 + lg * 16));
        o[0][bj] = __builtin_amdgcn_mfma_f32_16x16x32_bf16(pa[0][k32], vf, o[0][bj], 0, 0, 0);
        o[1][bj] = __builtin_amdgcn_mfma_f32_16x16x32_bf16(pa[1][k32], vf, o[1][bj], 0, 0, 0);
      }
  };

  auto body2 = [&](int buf) {
    const ushort* kb0 = k_lds + (2 * buf) * 4096;
    const ushort* kb1 = k_lds + (2 * buf + 1) * 4096;
    const ushort* vb0 = v_lds + (2 * buf) * 4096;
    const ushort* vb1 = v_lds + (2 * buf + 1) * 4096;
    f32x4 s0[2][4], s1[2][4];
    bf16x8 pa0[2][2], pa1[2][2];
    qk_sub(kb0, s0);
    qk_sub(kb1, s1);
    exp_pack(s0, pa0);
    pv_only(vb0, pa0);
    exp_pack(s1, pa1);
    pv_only(vb1, pa1);
    __builtin_amdgcn_sched_group_barrier(0x020, 8, 0);   // stage VMEM first
    __builtin_amdgcn_sched_group_barrier(0x100, 8, 0);   // K0 ds_reads
    __builtin_amdgcn_sched_group_barrier(0x008, 16, 0);  // QK(s0)
    __builtin_amdgcn_sched_group_barrier(0x100, 8, 0);   // K1 ds_reads
#pragma unroll
    for (int i = 0; i < 16; ++i) {                       // QK(s1) || exp(s0)
      __builtin_amdgcn_sched_group_barrier(0x008, 1, 0);
      __builtin_amdgcn_sched_group_barrier(0x002, 4, 0);
    }
    __builtin_amdgcn_sched_group_barrier(0x100, 8, 0);   // V0 ds_reads
#pragma unroll
    for (int i = 0; i < 20; ++i) {                       // PV(s0) || exp(s1)
      __builtin_amdgcn_sched_group_barrier(0x008, 1, 0);
      __builtin_amdgcn_sched_group_barrier(0x002, 3, 0);
    }
    __builtin_amdgcn_sched_group_barrier(0x100, 8, 0);   // V1 ds_reads
    __builtin_amdgcn_sched_group_barrier(0x008, 20, 0);  // PV(s1)
  };

  stage2(0, 0);
  __syncthreads();

  for (int tt = 0; tt < 8; ++tt) {
    stage2(1, (2 * tt + 1) * 128);
    body2(0);
    __syncthreads();
    if (tt < 7) stage2(0, (2 * tt + 2) * 128);
    body2(1);
    __syncthreads();
  }

#pragma unroll
  for (int qi = 0; qi < 2; ++qi) {
    f32x4 inv;
#pragma unroll
    for (int r = 0; r < 4; ++r) inv[r] = 1.0f / ssum[qi][r];
#pragma unroll
    for (int bj = 0; bj < 4; ++bj)
#pragma unroll
      for (int r = 0; r < 4; ++r) {
        int n = n0 + w * 32 + qi * 16 + lg * 4 + r;
        og[(size_t)(b * 2048 + n) * 1024 + h * 64 + bj * 16 + l15] = f2bf(o[qi][bj][r] * inv[r]);
      }
  }
}

// ---------------- launch ----------------

extern "C" void kernel_launch(void* const* d_in, const int* in_sizes, int n_in,
                              void* d_out, int out_size, void* d_ws, size_t ws_size,
                              hipStream_t stream) {
  const float* x = (const float*)d_in[0];
  const float* Wq = (const float*)d_in[1];
  const float* Wk = (const float*)d_in[2];
  const float* Wv = (const float*)d_in[3];
  const float* Wp = (const float*)d_in[4];
  float* y = (float*)d_out;

  char* ws = (char*)d_ws;
  ushort* xb = (ushort*)(ws);
  ushort* wT = (ushort*)(ws + (8ull << 20));
  ushort* qw = (ushort*)(ws + (16ull << 20));
  ushort* kw = (ushort*)(ws + (24ull << 20));
  ushort* vtw = (ushort*)(ws + (32ull << 20));
  ushort* ow = (ushort*)(ws);  // reuse xb region (dead after gemm_qkv)

  prep<<<dim3(32, 32, 8), dim3(8, 32), 0, stream>>>(x, Wq, Wk, Wv, Wp, xb, wT);
  gemm_qkv<<<512, 256, 0, stream>>>(xb, wT, qw, kw, vtw);
  attn<<<512, 256, 0, stream>>>(qw, kw, vtw, ow);
  gemm_out<<<1024, 256, 0, stream>>>(ow, wT + (3u << 20), x, y);
}